// Round 2
// 455.152 us; speedup vs baseline: 1.1834x; 1.1834x over previous
//
#include <hip/hip_runtime.h>
#include <math.h>

// Problem constants
#define Bn  16
#define ICn 16
#define Dn  16
#define Hn  128
#define Wn  128
#define OCn 32
#define DPn 14
#define HPn 126
#define WPn 126

typedef _Float16 half_t;
typedef __attribute__((ext_vector_type(8)))  _Float16 half8;
typedef __attribute__((ext_vector_type(16))) float    float16v;

// Tile config: wg = 4 waves; each wave: 32 pixels (2 rows x 16 cols) x 32 oc.
#define TH 8            // output rows per wg (4 waves x 2 rows)
#define TW 16           // output cols per wg
#define SR 10           // staged rows  (TH + 2 halo)
#define SCW 20          // staged cols  (TW + 2 halo, padded to 20 so rows are 5 x 16B chunks)
#define SLOT_B 16384    // 1024 chunks x 16B (800 real = [ic16][row10][col20] f32, 224 pad)
#define EP_PAD 33       // epilogue transpose pad (33 dwords -> conflict-free)

// ---------------------------------------------------------------------------
// Async DMA: one 16B chunk per lane, LDS dest = uniform base + lane*16.
// LDS slot layout (f32): [ic (stride 800B)][row (stride 80B)][col (stride 4B)]
// which is exactly linear chunk order: chunk c = ic*50 + row*5 + cq.
// ---------------------------------------------------------------------------
__device__ __forceinline__ void gl_lds16(const void* g, void* l) {
    __builtin_amdgcn_global_load_lds(
        (const __attribute__((address_space(1))) unsigned int*)g,
        (__attribute__((address_space(3))) unsigned int*)l, 16, 0, 0);
}

#define WAITV(N) asm volatile("s_waitcnt vmcnt(" #N ")" ::: "memory")
#define PHASE_END(N) do {                         \
    WAITV(N);                                     \
    __builtin_amdgcn_sched_barrier(0);            \
    __builtin_amdgcn_s_barrier();                 \
    __builtin_amdgcn_sched_barrier(0);            \
} while (0)

// ---------------------------------------------------------------------------
// Pack weights into B-fragment order for mfma_f32_32x32x16_f16:
//   B-frag: lane l holds B[n = l&31][k = (l>>5)*8 + j], j=0..7  (n=oc, k=ic)
//   wB[tap][lane][j] f16, tap = kd*9 + kh*3 + kw
// ---------------------------------------------------------------------------
__global__ void pack_w_kernel(const float* __restrict__ w, half_t* __restrict__ wB) {
    int i = blockIdx.x * 256 + threadIdx.x;      // over 27*64*8 = 13824
    if (i >= 27 * 64 * 8) return;
    int tap = i >> 9;                            // /512
    int l   = (i >> 3) & 63;
    int j   = i & 7;
    int oc  = l & 31;
    int ic  = ((l >> 5) << 3) + j;
    wB[i] = (half_t)w[(oc * ICn + ic) * 27 + tap];
}

// ---------------------------------------------------------------------------
// One staged plane, 9 spatial taps, each A-frag feeds up to 3 accumulators
// (kd=0 -> acc[A0], kd=1 -> acc[A1], kd=2 -> acc[A2]; -1 = skip).
// A-frag: 8 ic (= 8h + j) as f32 at stride 200 floats, converted to f16 here.
// ---------------------------------------------------------------------------
template<int A0, int A1, int A2>
__device__ __forceinline__ void mfma_plane(const float* p0, const half8* wf,
                                           float16v (&acc)[3]) {
#pragma unroll
    for (int kh = 0; kh < 3; ++kh) {
#pragma unroll
        for (int kw = 0; kw < 3; ++kw) {
            const float* p = p0 + kh * SCW + kw;
            half8 a;
#pragma unroll
            for (int j = 0; j < 8; ++j) a[j] = (half_t)p[j * 200];
            const int t = kh * 3 + kw;
            if constexpr (A0 >= 0)
                acc[A0] = __builtin_amdgcn_mfma_f32_32x32x16_f16(a, wf[t],      acc[A0], 0, 0, 0);
            if constexpr (A1 >= 0)
                acc[A1] = __builtin_amdgcn_mfma_f32_32x32x16_f16(a, wf[9 + t],  acc[A1], 0, 0, 0);
            if constexpr (A2 >= 0)
                acc[A2] = __builtin_amdgcn_mfma_f32_32x32x16_f16(a, wf[18 + t], acc[A2], 0, 0, 0);
        }
    }
}

#define FIN(i) do {                                                        \
    _Pragma("unroll")                                                      \
    for (int r = 0; r < 16; ++r) {                                         \
        mn[r] = fminf(mn[r], acc[i][r]);                                   \
        acc[i][r] = 0.0f;                                                  \
    }                                                                      \
} while (0)

// ---------------------------------------------------------------------------
// Fused implicit-GEMM conv3d -> min(depth) -> softmax(channels), f16 MFMA.
// Plane-centric loop: plane d feeds acc[(d-kd)%3] for kd=0..2; each plane is
// staged once (async DMA, 3-slot ring, counted vmcnt) and its 9 A-frags are
// loaded once from LDS and reused for all 3 kd taps.
//
// vmcnt ledger (per wave, 4 DMA issues per phase, uniform):
//   prologue: issue p0,p1 (after wf loads) -> WAITV(4): p0 + all older done.
//   phase d (d=0..13): issue p(d+2) -> compute plane d -> WAITV(4): all but
//     the 4 newest done => p(d+1) landed -> s_barrier -> rotate.
//   phase 14: no issue -> WAITV(0) => p15 landed. phase 15: no wait.
// Slot ring: plane d lives in slot d%3 (issue targets slot (d+2)%3, which was
// last read at phase d-1, freed by that phase's barrier).
// ---------------------------------------------------------------------------
__launch_bounds__(256, 2)
__global__ void conv_min_softmax_mfma(const float* __restrict__ x,
                                      const half_t* __restrict__ wB,
                                      const float* __restrict__ bias,
                                      float* __restrict__ out) {
    __shared__ __align__(16) char smem[3 * SLOT_B];

    const int tid  = threadIdx.x;
    const int lane = tid & 63;
    const int wv   = tid >> 6;                    // wave 0..3 -> rows 2wv..2wv+1

    // ---- XCD-contiguous block swizzle (bijective: 2048 % 8 == 0) ----
    // XCD k gets a contiguous range of work ids -> whole batch xy-planes per
    // XCD -> halo re-reads become L2 hits.
    int hlin = blockIdx.x + (blockIdx.y << 3) + (blockIdx.z << 7);   // 0..2047
    int wlin = ((hlin & 7) << 8) + (hlin >> 3);
    const int wpbase = (wlin & 7) << 4;
    const int hpbase = ((wlin >> 3) & 15) << 3;
    const int b      = wlin >> 7;

    const char* xb = (const char*)x + ((size_t)b << 24);   // b * 16 MiB

    // ---- per-thread DMA source byte offsets (plane 0), 4 chunks/thread ----
    // chunk c = ic*50 + row*5 + cq ; pad chunks (c>=800) re-read chunk 799.
    unsigned goff[4];
#pragma unroll
    for (int k = 0; k < 4; ++k) {
        int c = tid + (k << 8); if (c > 799) c = 799;
        int ic = c / 50, rem = c - ic * 50;
        int row = rem / 5, cq = rem - row * 5;
        int gr = hpbase + row; if (gr > 127) gr = 127;          // clamp halo rows
        int gc = wpbase + (cq << 2); if (gc > 124) gc = 124;    // clamp halo chunk
        goff[k] = ((unsigned)ic << 20) + ((unsigned)gr << 9) + ((unsigned)gc << 2);
    }

    auto issue4 = [&](const char* gb, int so) {
#pragma unroll
        for (int k = 0; k < 4; ++k)
            gl_lds16(gb + goff[k], smem + so + ((tid + (k << 8)) << 4));
        __builtin_amdgcn_sched_barrier(0);   // pin issues at phase start
    };

    // ---- preload all 27 tap B-fragments into VGPRs (coalesced dwordx4) ----
    half8 wf[27];
#pragma unroll
    for (int t = 0; t < 27; ++t)
        wf[t] = *(const half8*)(wB + (((size_t)t << 6) + lane) * 8);

    const float bv = bias[lane & 31];

    // ---- prologue: issue planes 0,1 ----
    const char* gcur = xb;
    issue4(gcur, 0);          gcur += 65536;   // p0 -> slot0
    issue4(gcur, SLOT_B);     gcur += 65536;   // p1 -> slot1

    // A-frag lane decode: m = lane&31 -> pixel (prow=m>>4, pcol=m&15); h = lane>>5
    const int m    = lane & 31;
    const int h    = lane >> 5;
    const int prow = m >> 4, pcol = m & 15;
    const int ibf  = h * 1600 + (2 * wv + prow) * SCW + pcol;   // float index
    const float* sA0 = (const float*)(smem) + ibf;
    const float* sA1 = (const float*)(smem + SLOT_B) + ibf;
    const float* sA2 = (const float*)(smem + 2 * SLOT_B) + ibf;

    float16v acc[3], mn;
#pragma unroll
    for (int r = 0; r < 16; ++r) {
        acc[0][r] = 0.0f; acc[1][r] = 0.0f; acc[2][r] = 0.0f;
        mn[r] = INFINITY;
    }

    WAITV(4);                                   // p0 (and wf/bias) landed
    __builtin_amdgcn_sched_barrier(0);
    __builtin_amdgcn_s_barrier();
    __builtin_amdgcn_sched_barrier(0);

    // d=0: kd0 -> acc0
    issue4(gcur, 2 * SLOT_B); gcur += 65536;    // p2 -> slot2
    mfma_plane<0, -1, -1>(sA0, wf, acc);
    PHASE_END(4);
    // d=1: kd0 -> acc1, kd1 -> acc0
    issue4(gcur, 0);          gcur += 65536;    // p3 -> slot0
    mfma_plane<1, 0, -1>(sA1, wf, acc);
    PHASE_END(4);

#pragma unroll 1
    for (int t3 = 0; t3 < 4; ++t3) {
        // d = 2+3t (slot2): kd0->acc2, kd1->acc1, kd2->acc0; finish dp=d-2
        issue4(gcur, SLOT_B);     gcur += 65536;
        mfma_plane<2, 1, 0>(sA2, wf, acc);
        FIN(0);
        PHASE_END(4);
        // d = 3+3t (slot0): kd0->acc0, kd1->acc2, kd2->acc1
        issue4(gcur, 2 * SLOT_B); gcur += 65536;
        mfma_plane<0, 2, 1>(sA0, wf, acc);
        FIN(1);
        PHASE_END(4);
        // d = 4+3t (slot1): kd0->acc1, kd1->acc0, kd2->acc2
        issue4(gcur, 0);          gcur += 65536;
        mfma_plane<1, 0, 2>(sA1, wf, acc);
        FIN(2);
        PHASE_END(4);
    }
    // d=14 (slot2): kd1->acc1, kd2->acc0; finish dp=12
    mfma_plane<-1, 1, 0>(sA2, wf, acc);
    FIN(0);
    PHASE_END(0);                               // drain: p15 landed
    // d=15 (slot0): kd2->acc1; finish dp=13
    mfma_plane<-1, -1, 1>(sA0, wf, acc);
    FIN(1);

    __syncthreads();                            // all slot reads done -> reuse LDS

    // ---- epilogue: bias + softmax over oc (32-lane shfl), transpose via LDS ----
    const int oc = m;                           // C/D: col(n=oc) = lane&31
    float* ep = (float*)smem;

#pragma unroll
    for (int reg = 0; reg < 16; ++reg) {
        float v = mn[reg] + bv;
        float mx = v;
#pragma unroll
        for (int off = 1; off < 32; off <<= 1)
            mx = fmaxf(mx, __shfl_xor(mx, off, 64));
        float e = __expf(v - mx);
        float s = e;
#pragma unroll
        for (int off = 1; off < 32; off <<= 1)
            s += __shfl_xor(s, off, 64);
        float pr = e / s;
        int mc = (reg & 3) + ((reg >> 2) << 3) + 4 * h;    // C/D row (pixel index)
        ep[(wv * 32 + mc) * EP_PAD + oc] = pr;
    }
    __syncthreads();

    // coalesced stores: [oc][row][col] runs of 16 contiguous floats
    for (int i = tid; i < 32 * TH * TW; i += 256) {        // 4096
        int oc2  = i >> 7;
        int rrow = (i >> 4) & 7;
        int col  = i & 15;
        int wvs = rrow >> 1, pr2 = rrow & 1;
        int mc  = pr2 * 16 + col;
        float val = ep[(wvs * 32 + mc) * EP_PAD + oc2];
        int hp = hpbase + rrow, wp = wpbase + col;
        if (hp < HPn && wp < WPn)
            out[((b * OCn + oc2) * HPn + hp) * WPn + wp] = val;
    }
}

extern "C" void kernel_launch(void* const* d_in, const int* in_sizes, int n_in,
                              void* d_out, int out_size, void* d_ws, size_t ws_size,
                              hipStream_t stream) {
    const float* x    = (const float*)d_in[0];
    const float* w    = (const float*)d_in[1];
    const float* bias = (const float*)d_in[2];
    float* out        = (float*)d_out;
    half_t* wB        = (half_t*)d_ws;           // 13824 f16 = 27.6 KB scratch

    {
        int n = 27 * 64 * 8;
        pack_w_kernel<<<(n + 255) / 256, 256, 0, stream>>>(w, wB);
    }
    {
        dim3 grid((WPn + TW - 1) / TW,           // 8 col-blocks
                  (HPn + TH - 1) / TH,           // 16 row-blocks
                  Bn);                           // 16 batches
        conv_min_softmax_mfma<<<grid, 256, 0, stream>>>(x, wB, bias, out);
    }
}